// Round 7
// baseline (160.290 us; speedup 1.0000x reference)
//
#include <hip/hip_runtime.h>
#include <hip/hip_bf16.h>

typedef __bf16 bf16x8 __attribute__((ext_vector_type(8)));
typedef __bf16 bf16x4 __attribute__((ext_vector_type(4)));
typedef float  f32x4  __attribute__((ext_vector_type(4)));

#define HF 128          // hidden dim
#define W1K 256         // W1 inner dim (2H)

// ============ Kernel 1: per-node linear precompute (v6: 256thr/32KB blocks)
// u[n] = A . x_src[n],  v[n] = B . x_dst[n]    (W1 = [A | B]; b1 added in k2)
// R6 finding: 512-thr/64KB blocks stuck at ~5 waves/CU (occupancy 15-17%),
// latency-bound at ~2 TB/s. v6: 256-thr blocks, 32KB LDS (one W half per
// block, blockIdx parity), __launch_bounds__(256,4) -> 4 blocks x 4 waves
// = 16 waves/CU, LDS 128KB/CU, VGPR cap 128 (112 used, no spill).
__global__ __launch_bounds__(256, 4) void node_precompute6(
    const float* __restrict__ x_src, const float* __restrict__ x_dst,
    const float* __restrict__ W1,
    __bf16* __restrict__ u, __bf16* __restrict__ v, int nNodes)
{
    __shared__ __align__(16) __bf16 wlds[32 * 64 * 8];   // 32 KiB

    const int tid  = threadIdx.x;
    const int lane = tid & 63;
    const int wid  = tid >> 6;      // 0..3
    const int l15  = lane & 15;
    const int lg   = lane >> 4;

    const int h = blockIdx.x & 1;   // 0 -> u/A, 1 -> v/B
    const float* __restrict__ x = h ? x_dst : x_src;
    __bf16* __restrict__ outp = h ? v : u;

    // ---- stage this half's W: fp32 global -> bf16 LDS, A-fragment order ----
    // frag f = mt*4 + kk : W[row = mt*16+l15][k = kk*32+lg*8 .. +8]
    for (int f = wid; f < 32; f += 4) {
        const int mt = f >> 2;
        const int kk = f & 3;
        const float* p = W1 + h * HF + (size_t)(mt * 16 + l15) * W1K
                       + kk * 32 + lg * 8;
        f32x4 a = *reinterpret_cast<const f32x4*>(p);
        f32x4 b = *reinterpret_cast<const f32x4*>(p + 4);
        bf16x8 w8;
        #pragma unroll
        for (int i = 0; i < 4; ++i) {
            w8[i]     = (__bf16)a[i];
            w8[i + 4] = (__bf16)b[i];
        }
        *reinterpret_cast<bf16x8*>(&wlds[(f * 64 + lane) * 8]) = w8;
    }
    __syncthreads();

    const int nst    = nNodes >> 4;           // 6250 subtiles for this half
    const int stride = (gridDim.x >> 1) * 4;  // wave-slots per half
    int st = (blockIdx.x >> 1) * 4 + wid;
    if (st >= nst) return;

    // prefetch first subtile's x rows
    f32x4 nxt[8];
    {
        const float* rp = x + (size_t)(st * 16 + l15) * HF + lg * 8;
        #pragma unroll
        for (int kk = 0; kk < 4; ++kk) {
            nxt[2 * kk]     = *reinterpret_cast<const f32x4*>(rp + kk * 32);
            nxt[2 * kk + 1] = *reinterpret_cast<const f32x4*>(rp + kk * 32 + 4);
        }
    }

    while (st < nst) {
        const int st2 = st + stride;

        // pack current x into bf16 B-fragments
        bf16x8 xb[4];
        #pragma unroll
        for (int kk = 0; kk < 4; ++kk) {
            bf16x8 t;
            #pragma unroll
            for (int i = 0; i < 4; ++i) {
                t[i]     = (__bf16)nxt[2 * kk][i];
                t[i + 4] = (__bf16)nxt[2 * kk + 1][i];
            }
            xb[kk] = t;
        }

        // prefetch next subtile (latency hides under MFMA + stores)
        if (st2 < nst) {
            const float* rp = x + (size_t)(st2 * 16 + l15) * HF + lg * 8;
            #pragma unroll
            for (int kk = 0; kk < 4; ++kk) {
                nxt[2 * kk]     = *reinterpret_cast<const f32x4*>(rp + kk * 32);
                nxt[2 * kk + 1] = *reinterpret_cast<const f32x4*>(rp + kk * 32 + 4);
            }
        }

        f32x4 acc[8];
        #pragma unroll
        for (int mt = 0; mt < 8; ++mt) acc[mt] = (f32x4){0.f, 0.f, 0.f, 0.f};

        #pragma unroll
        for (int kk = 0; kk < 4; ++kk)
            #pragma unroll
            for (int mt = 0; mt < 8; ++mt) {
                bf16x8 wa = *reinterpret_cast<const bf16x8*>(
                    &wlds[((mt * 4 + kk) * 64 + lane) * 8]);
                acc[mt] = __builtin_amdgcn_mfma_f32_16x16x32_bf16(
                    wa, xb[kk], acc[mt], 0, 0, 0);
            }

        // store: node = st*16 + l15, channels mt*16 + lg*4 .. +4
        __bf16* op = outp + (size_t)(st * 16 + l15) * HF + lg * 4;
        #pragma unroll
        for (int mt = 0; mt < 8; ++mt) {
            bf16x4 o4;
            #pragma unroll
            for (int r = 0; r < 4; ++r) o4[r] = (__bf16)acc[mt][r];
            *reinterpret_cast<bf16x4*>(op + mt * 16) = o4;
        }
        st = st2;
    }
}

// ================= Kernel 2: per-edge score (pure gather) =================
// score[e] = W2 . relu(u[src[e]] + v[dst[e]] + b1) + b2
// 16 lanes per edge, 8 channels (16 B bf16) per lane, 4 edges per subgroup.
__global__ __launch_bounds__(256) void edge_score_kernel(
    const __bf16* __restrict__ u, const __bf16* __restrict__ v,
    const int* __restrict__ sidx, const int* __restrict__ didx,
    const float* __restrict__ W2, const float* __restrict__ b1,
    const float* __restrict__ b2,
    float* __restrict__ out, int nEdges)
{
    const int tid = threadIdx.x;
    const int sub = tid >> 4;        // 0..15
    const int l16 = tid & 15;

    const int ebase = blockIdx.x * 64 + sub;   // edges ebase + {0,16,32,48}

    float w2v[8], b1v[8];
    #pragma unroll
    for (int j = 0; j < 8; ++j) {
        w2v[j] = W2[l16 * 8 + j];
        b1v[j] = b1[l16 * 8 + j];
    }
    const float b2v = b2[0];

    int e[4], si[4], di[4];
    #pragma unroll
    for (int q = 0; q < 4; ++q) {
        e[q] = ebase + q * 16;
        const int c = min(e[q], nEdges - 1);
        si[q] = sidx[c];
        di[q] = didx[c];
    }

    bf16x8 uv[4], vv[4];
    #pragma unroll
    for (int q = 0; q < 4; ++q) {
        uv[q] = *reinterpret_cast<const bf16x8*>(u + (size_t)si[q] * HF + l16 * 8);
        vv[q] = *reinterpret_cast<const bf16x8*>(v + (size_t)di[q] * HF + l16 * 8);
    }

    float s[4] = {0.f, 0.f, 0.f, 0.f};
    #pragma unroll
    for (int q = 0; q < 4; ++q)
        #pragma unroll
        for (int j = 0; j < 8; ++j)
            s[q] += fmaxf((float)uv[q][j] + (float)vv[q][j] + b1v[j], 0.f) * w2v[j];

    #pragma unroll
    for (int off = 1; off < 16; off <<= 1)
        #pragma unroll
        for (int q = 0; q < 4; ++q)
            s[q] += __shfl_xor(s[q], off, 64);

    if (l16 == 0) {
        #pragma unroll
        for (int q = 0; q < 4; ++q)
            if (e[q] < nEdges) out[e[q]] = s[q] + b2v;
    }
}

// ================= Fallback: fused single kernel (round-1) =================
__global__ __launch_bounds__(256, 2) void edge_mlp_kernel(
    const float* __restrict__ x_src, const float* __restrict__ x_dst,
    const int*   __restrict__ src_idx, const int* __restrict__ dst_idx,
    const float* __restrict__ W1, const float* __restrict__ b1,
    const float* __restrict__ W2, const float* __restrict__ b2,
    float* __restrict__ out, int nEdges)
{
    __shared__ __align__(16) __bf16 w1lds[64 * 64 * 8];

    const int tid  = threadIdx.x;
    const int lane = tid & 63;
    const int wid  = tid >> 6;
    const int l15  = lane & 15;
    const int lg   = lane >> 4;

    for (int p = wid; p < 64; p += 4) {
        const int n   = p >> 3;
        const int kk  = p & 7;
        const float* src = W1 + (n * 16 + l15) * W1K + kk * 32 + lg * 8;
        bf16x8 w8;
        #pragma unroll
        for (int i = 0; i < 8; ++i) w8[i] = (__bf16)src[i];
        *reinterpret_cast<bf16x8*>(&w1lds[(p * 64 + lane) * 8]) = w8;
    }
    __syncthreads();

    float w2v[8], b1v[8];
    #pragma unroll
    for (int n = 0; n < 8; ++n) {
        w2v[n] = W2[n * 16 + l15];
        b1v[n] = b1[n * 16 + l15];
    }
    const float b2v = b2[0];

    const int ntiles = nEdges / 256;
    for (int t = blockIdx.x; t < ntiles; t += gridDim.x) {
        const int ebase = t * 256 + wid * 64;

        const float* srow[4];
        const float* drow[4];
        #pragma unroll
        for (int m = 0; m < 4; ++m) {
            const int e  = ebase + m * 16 + l15;
            srow[m] = x_src + (size_t)src_idx[e] * HF + lg * 8;
            drow[m] = x_dst + (size_t)dst_idx[e] * HF + lg * 8;
        }

        f32x4 acc[4][8];
        #pragma unroll
        for (int m = 0; m < 4; ++m)
            #pragma unroll
            for (int n = 0; n < 8; ++n)
                acc[m][n] = (f32x4){0.f, 0.f, 0.f, 0.f};

        #pragma unroll
        for (int kk = 0; kk < 8; ++kk) {
            bf16x8 a[4];
            #pragma unroll
            for (int m = 0; m < 4; ++m) {
                const float* p = (kk < 4) ? (srow[m] + kk * 32)
                                          : (drow[m] + (kk - 4) * 32);
                f32x4 u0 = *reinterpret_cast<const f32x4*>(p);
                f32x4 u1 = *reinterpret_cast<const f32x4*>(p + 4);
                bf16x8 av;
                #pragma unroll
                for (int i = 0; i < 4; ++i) {
                    av[i]     = (__bf16)u0[i];
                    av[i + 4] = (__bf16)u1[i];
                }
                a[m] = av;
            }
            #pragma unroll
            for (int n = 0; n < 8; ++n) {
                bf16x8 bfrag = *reinterpret_cast<const bf16x8*>(
                    &w1lds[((n * 8 + kk) * 64 + lane) * 8]);
                #pragma unroll
                for (int m = 0; m < 4; ++m) {
                    acc[m][n] = __builtin_amdgcn_mfma_f32_16x16x32_bf16(
                        a[m], bfrag, acc[m][n], 0, 0, 0);
                }
            }
        }

        #pragma unroll
        for (int m = 0; m < 4; ++m) {
            float part[4];
            #pragma unroll
            for (int r = 0; r < 4; ++r) {
                float s = 0.f;
                #pragma unroll
                for (int n = 0; n < 8; ++n) {
                    float hv = acc[m][n][r] + b1v[n];
                    s += fmaxf(hv, 0.f) * w2v[n];
                }
                part[r] = s;
            }
            #pragma unroll
            for (int off = 1; off < 16; off <<= 1) {
                #pragma unroll
                for (int r = 0; r < 4; ++r)
                    part[r] += __shfl_xor(part[r], off, 64);
            }
            if (l15 == m) {
                f32x4 v4 = { part[0] + b2v, part[1] + b2v,
                             part[2] + b2v, part[3] + b2v };
                *reinterpret_cast<f32x4*>(&out[ebase + m * 16 + lg * 4]) = v4;
            }
        }
    }
}

extern "C" void kernel_launch(void* const* d_in, const int* in_sizes, int n_in,
                              void* d_out, int out_size, void* d_ws, size_t ws_size,
                              hipStream_t stream) {
    const float* x_src  = (const float*)d_in[0];
    const float* x_dst  = (const float*)d_in[1];
    const int*   sidx   = (const int*)d_in[2];
    const int*   didx   = (const int*)d_in[3];
    const float* W1     = (const float*)d_in[4];
    const float* b1     = (const float*)d_in[5];
    const float* W2     = (const float*)d_in[6];
    const float* b2     = (const float*)d_in[7];
    float* out = (float*)d_out;

    const int nEdges = in_sizes[2];
    const int nNodes = in_sizes[0] / HF;

    const size_t needed = (size_t)2 * nNodes * HF * sizeof(__bf16);  // u + v
    if (ws_size >= needed && (nNodes & 15) == 0) {
        __bf16* u = (__bf16*)d_ws;
        __bf16* v = u + (size_t)nNodes * HF;

        node_precompute6<<<2048, 256, 0, stream>>>(
            x_src, x_dst, W1, u, v, nNodes);

        const int egrid = (nEdges + 63) / 64;
        edge_score_kernel<<<egrid, 256, 0, stream>>>(
            u, v, sidx, didx, W2, b1, b2, out, nEdges);
    } else {
        edge_mlp_kernel<<<512, 256, 0, stream>>>(
            x_src, x_dst, sidx, didx, W1, b1, W2, b2, out, nEdges);
    }
}

// Round 8
// 116.645 us; speedup vs baseline: 1.3742x; 1.3742x over previous
//
#include <hip/hip_runtime.h>
#include <hip/hip_bf16.h>

typedef __bf16 bf16x8 __attribute__((ext_vector_type(8)));
typedef __bf16 bf16x4 __attribute__((ext_vector_type(4)));
typedef float  f32x4  __attribute__((ext_vector_type(4)));

#define HF 128          // hidden dim
#define W1K 256         // W1 inner dim (2H)

// ========== Kernel 0: one-time repack W1 fp32 -> bf16 MFMA-A-fragment order
// wf layout: [h][f=mt*4+kk][lane][8 bf16]; frag holds W[h][mt*16+l15][kk*32+lg*8 ..+8]
__global__ __launch_bounds__(256) void w1_repack(
    const float* __restrict__ W1, __bf16* __restrict__ wf)
{
    const int h    = blockIdx.x;        // 0 -> A (u), 1 -> B (v)
    const int tid  = threadIdx.x;
    const int lane = tid & 63;
    const int wid  = tid >> 6;
    const int l15  = lane & 15;
    const int lg   = lane >> 4;

    for (int f = wid; f < 32; f += 4) {
        const int mt = f >> 2;
        const int kk = f & 3;
        const float* p = W1 + h * HF + (size_t)(mt * 16 + l15) * W1K
                       + kk * 32 + lg * 8;
        f32x4 a = *reinterpret_cast<const f32x4*>(p);
        f32x4 b = *reinterpret_cast<const f32x4*>(p + 4);
        bf16x8 w8;
        #pragma unroll
        for (int i = 0; i < 4; ++i) {
            w8[i]     = (__bf16)a[i];
            w8[i + 4] = (__bf16)b[i];
        }
        *reinterpret_cast<bf16x8*>(wf + ((size_t)(h * 32 + f) * 64 + lane) * 8) = w8;
    }
}

// ========== Kernel 1: per-node linear precompute (v9: 64-VGPR, high-occ) ===
// u[n] = A . x_src[n],  v[n] = B . x_dst[n]   (b1 added in k2)
// Empirical law (R5/R7): __launch_bounds__(.,4) caps at 64 VGPR. Design the
// steady state to FIT 64: no cross-task prefetch (TLP hides latency), K
// processed in 4 slices with two 16-reg landing pads. W half staged into
// 32KB LDS from the pre-packed bf16 wf (pure 16B copies, L3-hot).
// Occupancy target: LDS 32KB -> 5 blocks/CU, VGPR 64 -> 8 waves/SIMD.
__global__ __launch_bounds__(256, 4) void node_precompute9(
    const float* __restrict__ x_src, const float* __restrict__ x_dst,
    const __bf16* __restrict__ wf,
    __bf16* __restrict__ u, __bf16* __restrict__ v, int nNodes)
{
    __shared__ __align__(16) __bf16 wlds[32 * 64 * 8];   // 32 KiB

    const int tid  = threadIdx.x;
    const int lane = tid & 63;
    const int wid  = tid >> 6;      // 0..3
    const int l15  = lane & 15;
    const int lg   = lane >> 4;

    const int h = blockIdx.x & 1;
    const float* __restrict__ xh = h ? x_dst : x_src;
    __bf16* __restrict__ oph = h ? v : u;

    // stage this half's pre-packed W fragments: pure 16-B copies
    {
        const __bf16* src = wf + (size_t)h * 32 * 64 * 8;
        for (int c = wid; c < 32; c += 4) {
            bf16x8 w8 = *reinterpret_cast<const bf16x8*>(src + (c * 64 + lane) * 8);
            *reinterpret_cast<bf16x8*>(&wlds[(c * 64 + lane) * 8]) = w8;
        }
    }
    __syncthreads();

    const int nst    = nNodes >> 4;           // 6250 (exact)
    const int stride = (gridDim.x >> 1) * 4;  // wave-slots per half
    const __bf16* fb = &wlds[lane * 8];       // + (mt*4+kk)*512 elems

    for (int st = (blockIdx.x >> 1) * 4 + wid; st < nst; st += stride) {
        const float* rp = xh + (size_t)(st * 16 + l15) * HF + lg * 8;
        __bf16*      op = oph + (size_t)(st * 16 + l15) * HF + lg * 4;

        f32x4 acc[8];
        #pragma unroll
        for (int mt = 0; mt < 8; ++mt) acc[mt] = (f32x4){0.f, 0.f, 0.f, 0.f};

        // K slices: kk pairs ping-ponged through two 16-reg landing pads
        f32x4 a0 = *reinterpret_cast<const f32x4*>(rp);
        f32x4 a1 = *reinterpret_cast<const f32x4*>(rp + 4);

        #pragma unroll
        for (int p = 0; p < 2; ++p) {
            const int k0 = 2 * p;
            // next slice into pad B
            f32x4 b0 = *reinterpret_cast<const f32x4*>(rp + (k0 + 1) * 32);
            f32x4 b1 = *reinterpret_cast<const f32x4*>(rp + (k0 + 1) * 32 + 4);
            {
                bf16x8 xb;
                #pragma unroll
                for (int i = 0; i < 4; ++i) {
                    xb[i]     = (__bf16)a0[i];
                    xb[i + 4] = (__bf16)a1[i];
                }
                #pragma unroll
                for (int mt = 0; mt < 8; ++mt) {
                    bf16x8 wa = *reinterpret_cast<const bf16x8*>(
                        fb + (mt * 4 + k0) * 512);
                    acc[mt] = __builtin_amdgcn_mfma_f32_16x16x32_bf16(
                        wa, xb, acc[mt], 0, 0, 0);
                }
            }
            if (p == 0) {   // next-next slice into pad A
                a0 = *reinterpret_cast<const f32x4*>(rp + 2 * 32);
                a1 = *reinterpret_cast<const f32x4*>(rp + 2 * 32 + 4);
            }
            {
                bf16x8 xb;
                #pragma unroll
                for (int i = 0; i < 4; ++i) {
                    xb[i]     = (__bf16)b0[i];
                    xb[i + 4] = (__bf16)b1[i];
                }
                #pragma unroll
                for (int mt = 0; mt < 8; ++mt) {
                    bf16x8 wa = *reinterpret_cast<const bf16x8*>(
                        fb + (mt * 4 + k0 + 1) * 512);
                    acc[mt] = __builtin_amdgcn_mfma_f32_16x16x32_bf16(
                        wa, xb, acc[mt], 0, 0, 0);
                }
            }
        }

        #pragma unroll
        for (int mt = 0; mt < 8; ++mt) {
            bf16x4 o4;
            #pragma unroll
            for (int r = 0; r < 4; ++r) o4[r] = (__bf16)acc[mt][r];
            *reinterpret_cast<bf16x4*>(op + mt * 16) = o4;
        }
    }
}

// ================= Kernel 2: per-edge score (pure gather) =================
// score[e] = W2 . relu(u[src[e]] + v[dst[e]] + b1) + b2
__global__ __launch_bounds__(256) void edge_score_kernel(
    const __bf16* __restrict__ u, const __bf16* __restrict__ v,
    const int* __restrict__ sidx, const int* __restrict__ didx,
    const float* __restrict__ W2, const float* __restrict__ b1,
    const float* __restrict__ b2,
    float* __restrict__ out, int nEdges)
{
    const int tid = threadIdx.x;
    const int sub = tid >> 4;        // 0..15
    const int l16 = tid & 15;

    const int ebase = blockIdx.x * 64 + sub;   // edges ebase + {0,16,32,48}

    float w2v[8], b1v[8];
    #pragma unroll
    for (int j = 0; j < 8; ++j) {
        w2v[j] = W2[l16 * 8 + j];
        b1v[j] = b1[l16 * 8 + j];
    }
    const float b2v = b2[0];

    int e[4], si[4], di[4];
    #pragma unroll
    for (int q = 0; q < 4; ++q) {
        e[q] = ebase + q * 16;
        const int c = min(e[q], nEdges - 1);
        si[q] = sidx[c];
        di[q] = didx[c];
    }

    bf16x8 uv[4], vv[4];
    #pragma unroll
    for (int q = 0; q < 4; ++q) {
        uv[q] = *reinterpret_cast<const bf16x8*>(u + (size_t)si[q] * HF + l16 * 8);
        vv[q] = *reinterpret_cast<const bf16x8*>(v + (size_t)di[q] * HF + l16 * 8);
    }

    float s[4] = {0.f, 0.f, 0.f, 0.f};
    #pragma unroll
    for (int q = 0; q < 4; ++q)
        #pragma unroll
        for (int j = 0; j < 8; ++j)
            s[q] += fmaxf((float)uv[q][j] + (float)vv[q][j] + b1v[j], 0.f) * w2v[j];

    #pragma unroll
    for (int off = 1; off < 16; off <<= 1)
        #pragma unroll
        for (int q = 0; q < 4; ++q)
            s[q] += __shfl_xor(s[q], off, 64);

    if (l16 == 0) {
        #pragma unroll
        for (int q = 0; q < 4; ++q)
            if (e[q] < nEdges) out[e[q]] = s[q] + b2v;
    }
}

// ================= Fallback: fused single kernel (round-1) =================
__global__ __launch_bounds__(256, 2) void edge_mlp_kernel(
    const float* __restrict__ x_src, const float* __restrict__ x_dst,
    const int*   __restrict__ src_idx, const int* __restrict__ dst_idx,
    const float* __restrict__ W1, const float* __restrict__ b1,
    const float* __restrict__ W2, const float* __restrict__ b2,
    float* __restrict__ out, int nEdges)
{
    __shared__ __align__(16) __bf16 w1lds[64 * 64 * 8];

    const int tid  = threadIdx.x;
    const int lane = tid & 63;
    const int wid  = tid >> 6;
    const int l15  = lane & 15;
    const int lg   = lane >> 4;

    for (int p = wid; p < 64; p += 4) {
        const int n   = p >> 3;
        const int kk  = p & 7;
        const float* src = W1 + (n * 16 + l15) * W1K + kk * 32 + lg * 8;
        bf16x8 w8;
        #pragma unroll
        for (int i = 0; i < 8; ++i) w8[i] = (__bf16)src[i];
        *reinterpret_cast<bf16x8*>(&w1lds[(p * 64 + lane) * 8]) = w8;
    }
    __syncthreads();

    float w2v[8], b1v[8];
    #pragma unroll
    for (int n = 0; n < 8; ++n) {
        w2v[n] = W2[n * 16 + l15];
        b1v[n] = b1[n * 16 + l15];
    }
    const float b2v = b2[0];

    const int ntiles = nEdges / 256;
    for (int t = blockIdx.x; t < ntiles; t += gridDim.x) {
        const int ebase = t * 256 + wid * 64;

        const float* srow[4];
        const float* drow[4];
        #pragma unroll
        for (int m = 0; m < 4; ++m) {
            const int e  = ebase + m * 16 + l15;
            srow[m] = x_src + (size_t)src_idx[e] * HF + lg * 8;
            drow[m] = x_dst + (size_t)dst_idx[e] * HF + lg * 8;
        }

        f32x4 acc[4][8];
        #pragma unroll
        for (int m = 0; m < 4; ++m)
            #pragma unroll
            for (int n = 0; n < 8; ++n)
                acc[m][n] = (f32x4){0.f, 0.f, 0.f, 0.f};

        #pragma unroll
        for (int kk = 0; kk < 8; ++kk) {
            bf16x8 a[4];
            #pragma unroll
            for (int m = 0; m < 4; ++m) {
                const float* p = (kk < 4) ? (srow[m] + kk * 32)
                                          : (drow[m] + (kk - 4) * 32);
                f32x4 u0 = *reinterpret_cast<const f32x4*>(p);
                f32x4 u1 = *reinterpret_cast<const f32x4*>(p + 4);
                bf16x8 av;
                #pragma unroll
                for (int i = 0; i < 4; ++i) {
                    av[i]     = (__bf16)u0[i];
                    av[i + 4] = (__bf16)u1[i];
                }
                a[m] = av;
            }
            #pragma unroll
            for (int n = 0; n < 8; ++n) {
                bf16x8 bfrag = *reinterpret_cast<const bf16x8*>(
                    &w1lds[((n * 8 + kk) * 64 + lane) * 8]);
                #pragma unroll
                for (int m = 0; m < 4; ++m) {
                    acc[m][n] = __builtin_amdgcn_mfma_f32_16x16x32_bf16(
                        a[m], bfrag, acc[m][n], 0, 0, 0);
                }
            }
        }

        #pragma unroll
        for (int m = 0; m < 4; ++m) {
            float part[4];
            #pragma unroll
            for (int r = 0; r < 4; ++r) {
                float s = 0.f;
                #pragma unroll
                for (int n = 0; n < 8; ++n) {
                    float hv = acc[m][n][r] + b1v[n];
                    s += fmaxf(hv, 0.f) * w2v[n];
                }
                part[r] = s;
            }
            #pragma unroll
            for (int off = 1; off < 16; off <<= 1) {
                #pragma unroll
                for (int r = 0; r < 4; ++r)
                    part[r] += __shfl_xor(part[r], off, 64);
            }
            if (l15 == m) {
                f32x4 v4 = { part[0] + b2v, part[1] + b2v,
                             part[2] + b2v, part[3] + b2v };
                *reinterpret_cast<f32x4*>(&out[ebase + m * 16 + lg * 4]) = v4;
            }
        }
    }
}

extern "C" void kernel_launch(void* const* d_in, const int* in_sizes, int n_in,
                              void* d_out, int out_size, void* d_ws, size_t ws_size,
                              hipStream_t stream) {
    const float* x_src  = (const float*)d_in[0];
    const float* x_dst  = (const float*)d_in[1];
    const int*   sidx   = (const int*)d_in[2];
    const int*   didx   = (const int*)d_in[3];
    const float* W1     = (const float*)d_in[4];
    const float* b1     = (const float*)d_in[5];
    const float* W2     = (const float*)d_in[6];
    const float* b2     = (const float*)d_in[7];
    float* out = (float*)d_out;

    const int nEdges = in_sizes[2];
    const int nNodes = in_sizes[0] / HF;

    const size_t uvsz   = (size_t)2 * nNodes * HF;                  // elems
    const size_t needed = uvsz * sizeof(__bf16) + 64 * 1024;        // u+v+wf
    if (ws_size >= needed && (nNodes & 15) == 0) {
        __bf16* u  = (__bf16*)d_ws;
        __bf16* v  = u + (size_t)nNodes * HF;
        __bf16* wf = u + uvsz;

        w1_repack<<<2, 256, 0, stream>>>(W1, wf);

        node_precompute9<<<1280, 256, 0, stream>>>(
            x_src, x_dst, wf, u, v, nNodes);

        const int egrid = (nEdges + 63) / 64;
        edge_score_kernel<<<egrid, 256, 0, stream>>>(
            u, v, sidx, didx, W2, b1, b2, out, nEdges);
    } else {
        edge_mlp_kernel<<<512, 256, 0, stream>>>(
            x_src, x_dst, sidx, didx, W1, b1, W2, b2, out, nEdges);
    }
}

// Round 9
// 87.641 us; speedup vs baseline: 1.8289x; 1.3309x over previous
//
#include <hip/hip_runtime.h>
#include <hip/hip_bf16.h>

typedef __bf16 bf16x8 __attribute__((ext_vector_type(8)));
typedef __bf16 bf16x4 __attribute__((ext_vector_type(4)));
typedef float  f32x4  __attribute__((ext_vector_type(4)));

#define HF 128          // hidden dim
#define W1K 256         // W1 inner dim (2H)

// ========== Kernel 0: one-time repack W1 fp32 -> bf16 MFMA-A-fragment order
// wf layout: [h][f=mt*4+kk][lane][8 bf16]; frag = W[h][mt*16+l15][kk*32+lg*8..+8]
__global__ __launch_bounds__(256) void w1_repack(
    const float* __restrict__ W1, __bf16* __restrict__ wf)
{
    const int h    = blockIdx.x;        // 0 -> A (u), 1 -> B (v)
    const int tid  = threadIdx.x;
    const int lane = tid & 63;
    const int wid  = tid >> 6;
    const int l15  = lane & 15;
    const int lg   = lane >> 4;

    for (int f = wid; f < 32; f += 4) {
        const int mt = f >> 2;
        const int kk = f & 3;
        const float* p = W1 + h * HF + (size_t)(mt * 16 + l15) * W1K
                       + kk * 32 + lg * 8;
        f32x4 a = *reinterpret_cast<const f32x4*>(p);
        f32x4 b = *reinterpret_cast<const f32x4*>(p + 4);
        bf16x8 w8;
        #pragma unroll
        for (int i = 0; i < 4; ++i) {
            w8[i]     = (__bf16)a[i];
            w8[i + 4] = (__bf16)b[i];
        }
        *reinterpret_cast<bf16x8*>(wf + ((size_t)(h * 32 + f) * 64 + lane) * 8) = w8;
    }
}

// ========== Kernel 1 (v10): async global_load_lds streaming GEMM ==========
// u[n] = A . x_src[n],  v[n] = B . x_dst[n]   (b1 added in k2)
// R5/R7/R8 lesson: register-prefetch always either spills (64-cap) or runs
// at ~4 waves/SIMD latency-bound. v10 moves latency hiding into the async
// DMA queue: per tile, 8x16B global_load_lds per thread (32KB in flight per
// CU >> BW*latency ~9KB), double-buffered; __syncthreads (vmcnt0) per tile.
// LDS: W both halves 64KB + X dbuf 2x32KB = 128KB -> 1 block/CU.
// X LDS granule-swizzle q^=(row&7): pre-swizzled global source + linear LDS
// dest (guide rule 21); ds_read_b128 hits the structural minimum.
__global__ __launch_bounds__(256, 1) void node_precompute10(
    const float* __restrict__ x_src, const float* __restrict__ x_dst,
    const __bf16* __restrict__ wf,
    __bf16* __restrict__ u, __bf16* __restrict__ v, int nNodes)
{
    __shared__ __align__(16) __bf16 wlds[2][32][64][8];   // 64 KiB
    __shared__ __align__(16) float  xlds[2][64 * HF];     // 2 x 32 KiB

    const int tid  = threadIdx.x;
    const int lane = tid & 63;
    const int wid  = tid >> 6;      // 0..3
    const int l15  = lane & 15;
    const int lg   = lane >> 4;

    // stage pre-packed W (both halves): pure 16-B copies, L3-hot
    {
        __bf16* wl = &wlds[0][0][0][0];
        for (int c = tid; c < 4096; c += 256) {
            bf16x8 w8 = *reinterpret_cast<const bf16x8*>(wf + (size_t)c * 8);
            *reinterpret_cast<bf16x8*>(wl + (size_t)c * 8) = w8;
        }
    }

    const int nth = (nNodes + 63) >> 6;     // 64-node tiles per half
    const int T   = nth * 2;                // tile t: h = t&1, trow = t>>1

    // ---- async stage: tile t -> xlds[buf] (linear dest, swizzled source) --
    auto STAGE = [&](int buf, int t) {
        const int h    = t & 1;
        const int trow = t >> 1;
        const float* __restrict__ xp = h ? x_dst : x_src;
        #pragma unroll
        for (int i = 0; i < 8; ++i) {
            const int G   = i * 256 + tid;          // 16-B granule 0..2047
            const int row = G >> 5;                  // 0..63
            const int q   = G & 31;
            const int qs  = q ^ (row & 7);           // inverse swizzle on src
            const int grow = min(trow * 64 + row, nNodes - 1);
            const float* src = xp + (size_t)grow * HF + qs * 4;
            __builtin_amdgcn_global_load_lds(
                (const __attribute__((address_space(1))) void*)src,
                (__attribute__((address_space(3))) void*)&xlds[buf][(size_t)G * 4],
                16, 0, 0);
        }
    };

    int t = blockIdx.x;
    if (t >= T) return;
    STAGE(0, t);
    __syncthreads();

    int buf = 0;
    while (t < T) {
        const int tn = t + gridDim.x;
        if (tn < T) STAGE(buf ^ 1, tn);

        // ---- compute tile t from xlds[buf] ----
        const int h    = t & 1;
        const int trow = t >> 1;
        const int row  = wid * 16 + l15;             // 0..63
        const int node = trow * 64 + row;

        f32x4 acc[8];
        #pragma unroll
        for (int mt = 0; mt < 8; ++mt) acc[mt] = (f32x4){0.f, 0.f, 0.f, 0.f};

        const float* xr = &xlds[buf][(size_t)row * HF];
        #pragma unroll
        for (int kk = 0; kk < 4; ++kk) {
            const int q0 = kk * 8 + lg * 2;
            f32x4 a0 = *reinterpret_cast<const f32x4*>(xr + ((q0)     ^ (row & 7)) * 4);
            f32x4 a1 = *reinterpret_cast<const f32x4*>(xr + ((q0 + 1) ^ (row & 7)) * 4);
            bf16x8 xb;
            #pragma unroll
            for (int i = 0; i < 4; ++i) {
                xb[i]     = (__bf16)a0[i];
                xb[i + 4] = (__bf16)a1[i];
            }
            #pragma unroll
            for (int mt = 0; mt < 8; ++mt) {
                bf16x8 wa = *reinterpret_cast<const bf16x8*>(&wlds[h][mt * 4 + kk][lane][0]);
                acc[mt] = __builtin_amdgcn_mfma_f32_16x16x32_bf16(
                    wa, xb, acc[mt], 0, 0, 0);
            }
        }

        if (node < nNodes) {
            __bf16* op = (h ? v : u) + (size_t)node * HF + lg * 4;
            #pragma unroll
            for (int mt = 0; mt < 8; ++mt) {
                bf16x4 o4;
                #pragma unroll
                for (int r = 0; r < 4; ++r) o4[r] = (__bf16)acc[mt][r];
                *reinterpret_cast<bf16x4*>(op + mt * 16) = o4;
            }
        }

        __syncthreads();   // drains vmcnt(0): next tile staged; buf safe to flip
        buf ^= 1;
        t = tn;
    }
}

// ================= Kernel 2: per-edge score (pure gather) =================
// score[e] = W2 . relu(u[src[e]] + v[dst[e]] + b1) + b2
__global__ __launch_bounds__(256) void edge_score_kernel(
    const __bf16* __restrict__ u, const __bf16* __restrict__ v,
    const int* __restrict__ sidx, const int* __restrict__ didx,
    const float* __restrict__ W2, const float* __restrict__ b1,
    const float* __restrict__ b2,
    float* __restrict__ out, int nEdges)
{
    const int tid = threadIdx.x;
    const int sub = tid >> 4;        // 0..15
    const int l16 = tid & 15;

    const int ebase = blockIdx.x * 64 + sub;   // edges ebase + {0,16,32,48}

    float w2v[8], b1v[8];
    #pragma unroll
    for (int j = 0; j < 8; ++j) {
        w2v[j] = W2[l16 * 8 + j];
        b1v[j] = b1[l16 * 8 + j];
    }
    const float b2v = b2[0];

    int e[4], si[4], di[4];
    #pragma unroll
    for (int q = 0; q < 4; ++q) {
        e[q] = ebase + q * 16;
        const int c = min(e[q], nEdges - 1);
        si[q] = sidx[c];
        di[q] = didx[c];
    }

    bf16x8 uv[4], vv[4];
    #pragma unroll
    for (int q = 0; q < 4; ++q) {
        uv[q] = *reinterpret_cast<const bf16x8*>(u + (size_t)si[q] * HF + l16 * 8);
        vv[q] = *reinterpret_cast<const bf16x8*>(v + (size_t)di[q] * HF + l16 * 8);
    }

    float s[4] = {0.f, 0.f, 0.f, 0.f};
    #pragma unroll
    for (int q = 0; q < 4; ++q)
        #pragma unroll
        for (int j = 0; j < 8; ++j)
            s[q] += fmaxf((float)uv[q][j] + (float)vv[q][j] + b1v[j], 0.f) * w2v[j];

    #pragma unroll
    for (int off = 1; off < 16; off <<= 1)
        #pragma unroll
        for (int q = 0; q < 4; ++q)
            s[q] += __shfl_xor(s[q], off, 64);

    if (l16 == 0) {
        #pragma unroll
        for (int q = 0; q < 4; ++q)
            if (e[q] < nEdges) out[e[q]] = s[q] + b2v;
    }
}

// ================= Fallback: fused single kernel (round-1) =================
__global__ __launch_bounds__(256, 2) void edge_mlp_kernel(
    const float* __restrict__ x_src, const float* __restrict__ x_dst,
    const int*   __restrict__ src_idx, const int* __restrict__ dst_idx,
    const float* __restrict__ W1, const float* __restrict__ b1,
    const float* __restrict__ W2, const float* __restrict__ b2,
    float* __restrict__ out, int nEdges)
{
    __shared__ __align__(16) __bf16 w1lds[64 * 64 * 8];

    const int tid  = threadIdx.x;
    const int lane = tid & 63;
    const int wid  = tid >> 6;
    const int l15  = lane & 15;
    const int lg   = lane >> 4;

    for (int p = wid; p < 64; p += 4) {
        const int n   = p >> 3;
        const int kk  = p & 7;
        const float* src = W1 + (n * 16 + l15) * W1K + kk * 32 + lg * 8;
        bf16x8 w8;
        #pragma unroll
        for (int i = 0; i < 8; ++i) w8[i] = (__bf16)src[i];
        *reinterpret_cast<bf16x8*>(&w1lds[(p * 64 + lane) * 8]) = w8;
    }
    __syncthreads();

    float w2v[8], b1v[8];
    #pragma unroll
    for (int n = 0; n < 8; ++n) {
        w2v[n] = W2[n * 16 + l15];
        b1v[n] = b1[n * 16 + l15];
    }
    const float b2v = b2[0];

    const int ntiles = nEdges / 256;
    for (int t = blockIdx.x; t < ntiles; t += gridDim.x) {
        const int ebase = t * 256 + wid * 64;

        const float* srow[4];
        const float* drow[4];
        #pragma unroll
        for (int m = 0; m < 4; ++m) {
            const int e  = ebase + m * 16 + l15;
            srow[m] = x_src + (size_t)src_idx[e] * HF + lg * 8;
            drow[m] = x_dst + (size_t)dst_idx[e] * HF + lg * 8;
        }

        f32x4 acc[4][8];
        #pragma unroll
        for (int m = 0; m < 4; ++m)
            #pragma unroll
            for (int n = 0; n < 8; ++n)
                acc[m][n] = (f32x4){0.f, 0.f, 0.f, 0.f};

        #pragma unroll
        for (int kk = 0; kk < 8; ++kk) {
            bf16x8 a[4];
            #pragma unroll
            for (int m = 0; m < 4; ++m) {
                const float* p = (kk < 4) ? (srow[m] + kk * 32)
                                          : (drow[m] + (kk - 4) * 32);
                f32x4 u0 = *reinterpret_cast<const f32x4*>(p);
                f32x4 u1 = *reinterpret_cast<const f32x4*>(p + 4);
                bf16x8 av;
                #pragma unroll
                for (int i = 0; i < 4; ++i) {
                    av[i]     = (__bf16)u0[i];
                    av[i + 4] = (__bf16)u1[i];
                }
                a[m] = av;
            }
            #pragma unroll
            for (int n = 0; n < 8; ++n) {
                bf16x8 bfrag = *reinterpret_cast<const bf16x8*>(
                    &w1lds[((n * 8 + kk) * 64 + lane) * 8]);
                #pragma unroll
                for (int m = 0; m < 4; ++m) {
                    acc[m][n] = __builtin_amdgcn_mfma_f32_16x16x32_bf16(
                        a[m], bfrag, acc[m][n], 0, 0, 0);
                }
            }
        }

        #pragma unroll
        for (int m = 0; m < 4; ++m) {
            float part[4];
            #pragma unroll
            for (int r = 0; r < 4; ++r) {
                float s = 0.f;
                #pragma unroll
                for (int n = 0; n < 8; ++n) {
                    float hv = acc[m][n][r] + b1v[n];
                    s += fmaxf(hv, 0.f) * w2v[n];
                }
                part[r] = s;
            }
            #pragma unroll
            for (int off = 1; off < 16; off <<= 1) {
                #pragma unroll
                for (int r = 0; r < 4; ++r)
                    part[r] += __shfl_xor(part[r], off, 64);
            }
            if (l15 == m) {
                f32x4 v4 = { part[0] + b2v, part[1] + b2v,
                             part[2] + b2v, part[3] + b2v };
                *reinterpret_cast<f32x4*>(&out[ebase + m * 16 + lg * 4]) = v4;
            }
        }
    }
}

extern "C" void kernel_launch(void* const* d_in, const int* in_sizes, int n_in,
                              void* d_out, int out_size, void* d_ws, size_t ws_size,
                              hipStream_t stream) {
    const float* x_src  = (const float*)d_in[0];
    const float* x_dst  = (const float*)d_in[1];
    const int*   sidx   = (const int*)d_in[2];
    const int*   didx   = (const int*)d_in[3];
    const float* W1     = (const float*)d_in[4];
    const float* b1     = (const float*)d_in[5];
    const float* W2     = (const float*)d_in[6];
    const float* b2     = (const float*)d_in[7];
    float* out = (float*)d_out;

    const int nEdges = in_sizes[2];
    const int nNodes = in_sizes[0] / HF;

    const size_t uvsz   = (size_t)2 * nNodes * HF;                  // elems
    const size_t needed = uvsz * sizeof(__bf16) + 64 * 1024;        // u+v+wf
    if (ws_size >= needed) {
        __bf16* u  = (__bf16*)d_ws;
        __bf16* v  = u + (size_t)nNodes * HF;
        __bf16* wf = u + uvsz;

        w1_repack<<<2, 256, 0, stream>>>(W1, wf);

        node_precompute10<<<256, 256, 0, stream>>>(
            x_src, x_dst, wf, u, v, nNodes);

        const int egrid = (nEdges + 63) / 64;
        edge_score_kernel<<<egrid, 256, 0, stream>>>(
            u, v, sidx, didx, W2, b1, b2, out, nEdges);
    } else {
        edge_mlp_kernel<<<512, 256, 0, stream>>>(
            x_src, x_dst, sidx, didx, W1, b1, W2, b2, out, nEdges);
    }
}